// Round 1
// baseline (4912.978 us; speedup 1.0000x reference)
//
#include <hip/hip_runtime.h>
#include <math.h>

#define H 64
#define W 64
#define HW 4096
#define CH 128
#define CIN 256
#define COUT 384
#define KDIM 1152   // CH*9
#define NB 4

// ---------------- copy former+latter passthrough ----------------
__global__ void copy_passthrough(const float* __restrict__ x, float* __restrict__ out) {
    int idx = blockIdx.x * blockDim.x + threadIdx.x; // over NB*CIN*HW
    if (idx >= NB * CIN * HW) return;
    int b = idx / (CIN * HW);
    int rem = idx - b * (CIN * HW);
    out[(size_t)b * COUT * HW + rem] = x[idx];
}

// ---------------- im2col of former -> P (HW x KDIM) ----------------
__global__ void build_patches(const float* __restrict__ former, float* __restrict__ P) {
    int idx = blockIdx.x * blockDim.x + threadIdx.x; // over HW*KDIM
    if (idx >= HW * KDIM) return;
    int i = idx / KDIM, k = idx - i * KDIM;
    int c = k / 9, q = k - c * 9;
    int dy = q / 3, dx = q - dy * 3;
    int y = (i >> 6) + dy - 1, x = (i & 63) + dx - 1;
    float v = 0.f;
    if ((unsigned)y < H && (unsigned)x < W) v = former[c * HW + y * W + x];
    P[idx] = v;
}

// ---------------- normalized latter windows + den + mm ----------------
__global__ void build_winn(const float* __restrict__ latter, const float* __restrict__ mask,
                           const int* __restrict__ mask_thred_p,
                           float* __restrict__ WN, float* __restrict__ den, float* __restrict__ mm) {
    int j = blockIdx.x;               // patch index
    int y0 = j >> 6, x0 = j & 63;
    __shared__ float red[256];
    float vals[5];
    float ss = 0.f;
    for (int t = 0; t < 5; ++t) {
        int k = threadIdx.x + t * 256;
        float v = 0.f;
        if (k < KDIM) {
            int c = k / 9, q = k - c * 9;
            int dy = q / 3, dx = q - dy * 3;
            int y = y0 + dy - 1, x = x0 + dx - 1;
            if ((unsigned)y < H && (unsigned)x < W) v = latter[c * HW + y * W + x];
        }
        vals[t] = v;
        ss += v * v;
    }
    red[threadIdx.x] = ss;
    __syncthreads();
    for (int s = 128; s > 0; s >>= 1) {
        if (threadIdx.x < s) red[threadIdx.x] += red[threadIdx.x + s];
        __syncthreads();
    }
    float d = fmaxf(sqrtf(red[0]), 1e-4f);
    float inv = 1.f / d;
    for (int t = 0; t < 5; ++t) {
        int k = threadIdx.x + t * 256;
        if (k < KDIM) WN[(size_t)j * KDIM + k] = vals[t] * inv;
    }
    if (threadIdx.x == 0) {
        den[j] = d;
        float s = 0.f;
        for (int q = 0; q < 9; ++q) {
            int dy = q / 3, dx = q - dy * 3;
            int y = y0 + dy - 1, x = x0 + dx - 1;
            if ((unsigned)y < H && (unsigned)x < W) s += mask[y * W + x];
        }
        float mmean = s / 9.f;
        float thr = (float)mask_thred_p[0] / 9.f;
        mm[j] = (mmean <= thr) ? 1.f : 0.f;
    }
}

// ---------------- tiled fp32 GEMM, C[M,N] = A[M,K] * B[N,K]^T ----------------
#define KT 16
__launch_bounds__(256)
__global__ void gemm_nt(const float* __restrict__ A, const float* __restrict__ B,
                        float* __restrict__ C, int M, int N, int Kd) {
    __shared__ float As[KT][68];
    __shared__ float Bs[KT][68];
    int tid = threadIdx.x;
    int ty = tid >> 4, tx = tid & 15;
    int i0 = blockIdx.y * 64, j0 = blockIdx.x * 64;
    int r = tid >> 2, cq = tid & 3;
    float acc[4][4] = {};
    for (int k0 = 0; k0 < Kd; k0 += KT) {
        float4 a4 = *(const float4*)(A + (size_t)(i0 + r) * Kd + k0 + cq * 4);
        float4 b4 = *(const float4*)(B + (size_t)(j0 + r) * Kd + k0 + cq * 4);
        As[cq * 4 + 0][r] = a4.x; As[cq * 4 + 1][r] = a4.y;
        As[cq * 4 + 2][r] = a4.z; As[cq * 4 + 3][r] = a4.w;
        Bs[cq * 4 + 0][r] = b4.x; Bs[cq * 4 + 1][r] = b4.y;
        Bs[cq * 4 + 2][r] = b4.z; Bs[cq * 4 + 3][r] = b4.w;
        __syncthreads();
        #pragma unroll
        for (int kk = 0; kk < KT; ++kk) {
            float4 av = *(const float4*)(&As[kk][ty * 4]);
            float4 bv = *(const float4*)(&Bs[kk][tx * 4]);
            float a[4] = {av.x, av.y, av.z, av.w};
            float b[4] = {bv.x, bv.y, bv.z, bv.w};
            #pragma unroll
            for (int u = 0; u < 4; ++u)
                #pragma unroll
                for (int v = 0; v < 4; ++v)
                    acc[u][v] += a[u] * b[v];
        }
        __syncthreads();
    }
    #pragma unroll
    for (int u = 0; u < 4; ++u) {
        int i = i0 + ty * 4 + u;
        float4 o = make_float4(acc[u][0], acc[u][1], acc[u][2], acc[u][3]);
        *(float4*)(C + (size_t)i * N + j0 + tx * 4) = o;
    }
}

// ---------------- tiled fp32 GEMM, C[M,N] = A[M,K] * B[K,N] ----------------
__launch_bounds__(256)
__global__ void gemm_nn(const float* __restrict__ A, const float* __restrict__ B,
                        float* __restrict__ C, int M, int N, int Kd) {
    __shared__ float As[KT][68];
    __shared__ float Bs[KT][68];
    int tid = threadIdx.x;
    int ty = tid >> 4, tx = tid & 15;
    int i0 = blockIdx.y * 64, n0 = blockIdx.x * 64;
    int r = tid >> 2, cq = tid & 3;
    int rb = tid >> 4, cb = tid & 15;
    float acc[4][4] = {};
    for (int k0 = 0; k0 < Kd; k0 += KT) {
        float4 a4 = *(const float4*)(A + (size_t)(i0 + r) * Kd + k0 + cq * 4);
        As[cq * 4 + 0][r] = a4.x; As[cq * 4 + 1][r] = a4.y;
        As[cq * 4 + 2][r] = a4.z; As[cq * 4 + 3][r] = a4.w;
        float4 b4 = *(const float4*)(B + (size_t)(k0 + rb) * N + n0 + cb * 4);
        *(float4*)(&Bs[rb][cb * 4]) = b4;
        __syncthreads();
        #pragma unroll
        for (int kk = 0; kk < KT; ++kk) {
            float4 av = *(const float4*)(&As[kk][ty * 4]);
            float4 bv = *(const float4*)(&Bs[kk][tx * 4]);
            float a[4] = {av.x, av.y, av.z, av.w};
            float b[4] = {bv.x, bv.y, bv.z, bv.w};
            #pragma unroll
            for (int u = 0; u < 4; ++u)
                #pragma unroll
                for (int v = 0; v < 4; ++v)
                    acc[u][v] += a[u] * b[v];
        }
        __syncthreads();
    }
    #pragma unroll
    for (int u = 0; u < 4; ++u) {
        int i = i0 + ty * 4 + u;
        float4 o = make_float4(acc[u][0], acc[u][1], acc[u][2], acc[u][3]);
        *(float4*)(C + (size_t)i * N + n0 + tx * 4) = o;
    }
}

// ---------------- double diag conv with exact flat-wrap semantics ----------------
// Y[i*HW + j] = sum_{d2,d1 in {-1,0,1}} S[i''*HW + j''] where the shift chain is:
// colmajor-flat shift by d2, then rowmajor-flat shift by d1, each zero-padded at [0,HW).
__global__ void diag_conv2(const float* __restrict__ S, float* __restrict__ Y) {
    int i = blockIdx.x;
    int iy = i >> 6, ix = i & 63;
    for (int j = threadIdx.x; j < HW; j += blockDim.x) {
        int jy = j >> 6, jx = j & 63;
        float s = 0.f;
        #pragma unroll
        for (int d2 = -1; d2 <= 1; ++d2) {
            int gi = ix * 64 + iy + d2;
            if ((unsigned)gi >= HW) continue;
            int gj = jx * 64 + jy + d2;
            if ((unsigned)gj >= HW) continue;
            int irm = (gi & 63) * 64 + (gi >> 6);
            int jrm = (gj & 63) * 64 + (gj >> 6);
            #pragma unroll
            for (int d1 = -1; d1 <= 1; ++d1) {
                int i2 = irm + d1;
                if ((unsigned)i2 >= HW) continue;
                int j2 = jrm + d1;
                if ((unsigned)j2 >= HW) continue;
                s += S[(size_t)i2 * HW + j2];
            }
        }
        Y[(size_t)i * HW + j] = s;
    }
}

// ---------------- row softmax (over j) + mm mask + den scaling, in place ----------------
__global__ void softmax_scale(float* __restrict__ Y, const float* __restrict__ mm,
                              const float* __restrict__ den) {
    int i = blockIdx.x;
    float* row = Y + (size_t)i * HW;
    __shared__ float red[256];
    float lv[16], mmv[16];
    float lmax = -1e30f;
    #pragma unroll
    for (int t = 0; t < 16; ++t) {
        int j = threadIdx.x + t * 256;
        float m = mm[j];
        float l = 10.f * row[j] * m;
        lv[t] = l; mmv[t] = m;
        lmax = fmaxf(lmax, l);
    }
    red[threadIdx.x] = lmax;
    __syncthreads();
    for (int s = 128; s > 0; s >>= 1) {
        if (threadIdx.x < s) red[threadIdx.x] = fmaxf(red[threadIdx.x], red[threadIdx.x + s]);
        __syncthreads();
    }
    float M = red[0];
    __syncthreads();
    float ev[16];
    float ssum = 0.f;
    #pragma unroll
    for (int t = 0; t < 16; ++t) {
        ev[t] = expf(lv[t] - M);
        ssum += ev[t];
    }
    red[threadIdx.x] = ssum;
    __syncthreads();
    for (int s = 128; s > 0; s >>= 1) {
        if (threadIdx.x < s) red[threadIdx.x] += red[threadIdx.x + s];
        __syncthreads();
    }
    float inv = 1.f / red[0];
    #pragma unroll
    for (int t = 0; t < 16; ++t) {
        int j = threadIdx.x + t * 256;
        row[j] = ev[t] * inv * mmv[t] * den[j];
    }
}

// ---------------- fold contrib (HW x KDIM) into shift output ----------------
__global__ void fold_out(const float* __restrict__ contrib, float* __restrict__ outb) {
    int idx = blockIdx.x * blockDim.x + threadIdx.x; // over CH*HW
    if (idx >= CH * HW) return;
    int c = idx >> 12;
    int pix = idx & 4095;
    int y = pix >> 6, x = pix & 63;
    float s = 0.f;
    #pragma unroll
    for (int dy = 0; dy < 3; ++dy)
        #pragma unroll
        for (int dx = 0; dx < 3; ++dx) {
            int yy = y + 1 - dy, xx = x + 1 - dx;
            if ((unsigned)yy < H && (unsigned)xx < W)
                s += contrib[(size_t)(yy * W + xx) * KDIM + c * 9 + dy * 3 + dx];
        }
    outb[(size_t)(CIN + c) * HW + pix] = s * (1.f / 9.f);
}

extern "C" void kernel_launch(void* const* d_in, const int* in_sizes, int n_in,
                              void* d_out, int out_size, void* d_ws, size_t ws_size,
                              hipStream_t stream) {
    const float* x = (const float*)d_in[0];
    const float* mask = (const float*)d_in[1];
    const int* mask_thred = (const int*)d_in[3];
    float* out = (float*)d_out;

    char* ws = (char*)d_ws;
    size_t off = 0;
    auto alloc = [&](size_t bytes) {
        char* p = ws + off;
        off = (off + bytes + 255) & ~(size_t)255;
        return p;
    };
    float* P   = (float*)alloc((size_t)HW * KDIM * 4);   // patches, then reused for contrib
    float* WN  = (float*)alloc((size_t)HW * KDIM * 4);   // normalized windows
    float* S   = (float*)alloc((size_t)HW * HW * 4);     // scores
    float* Y   = (float*)alloc((size_t)HW * HW * 4);     // diag-conv'd / cos
    float* den = (float*)alloc((size_t)HW * 4);
    float* mmb = (float*)alloc((size_t)HW * 4);

    copy_passthrough<<<(NB * CIN * HW + 255) / 256, 256, 0, stream>>>(x, out);

    for (int b = 0; b < NB; ++b) {
        const float* xb = x + (size_t)b * CIN * HW;
        const float* former = xb;
        const float* latter = xb + (size_t)CH * HW;
        const float* maskb = mask + (size_t)b * HW;
        float* outb = out + (size_t)b * COUT * HW;

        build_patches<<<(HW * KDIM + 255) / 256, 256, 0, stream>>>(former, P);
        build_winn<<<HW, 256, 0, stream>>>(latter, maskb, mask_thred, WN, den, mmb);
        gemm_nt<<<dim3(64, 64), 256, 0, stream>>>(P, WN, S, HW, HW, KDIM);
        diag_conv2<<<HW, 256, 0, stream>>>(S, Y);
        softmax_scale<<<HW, 256, 0, stream>>>(Y, mmb, den);
        gemm_nn<<<dim3(KDIM / 64, HW / 64), 256, 0, stream>>>(Y, WN, P, HW, KDIM, HW);
        fold_out<<<(CH * HW + 255) / 256, 256, 0, stream>>>(P, outb);
    }
}

// Round 2
// 1936.902 us; speedup vs baseline: 2.5365x; 2.5365x over previous
//
#include <hip/hip_runtime.h>
#include <math.h>

#define H 64
#define W 64
#define HW 4096
#define CH 128
#define CIN 256
#define COUT 384
#define KDIM 1152
#define K3 3456      // 3*KDIM for hi/lo split GEMM
#define NB 4

typedef __bf16 bf16x8 __attribute__((ext_vector_type(8)));
typedef float f32x4 __attribute__((ext_vector_type(4)));

__device__ __forceinline__ void gl_lds16(const __bf16* g, __bf16* l) {
    __builtin_amdgcn_global_load_lds(
        (const __attribute__((address_space(1))) unsigned int*)(g),
        (__attribute__((address_space(3))) unsigned int*)(l), 16, 0, 0);
}

// ---------------- copy former+latter passthrough ----------------
__global__ void copy_passthrough(const float* __restrict__ x, float* __restrict__ out) {
    int idx = blockIdx.x * blockDim.x + threadIdx.x; // over NB*CIN*HW
    if (idx >= NB * CIN * HW) return;
    int b = idx / (CIN * HW);
    int rem = idx - b * (CIN * HW);
    out[(size_t)b * COUT * HW + rem] = x[idx];
}

// ---------------- im2col of former -> A2 = [P_hi | P_lo | P_hi] ----------------
__global__ void build_patches_hilo(const float* __restrict__ former, __bf16* __restrict__ A2) {
    int idx = blockIdx.x * blockDim.x + threadIdx.x; // over HW*KDIM
    if (idx >= HW * KDIM) return;
    int i = idx / KDIM, k = idx - i * KDIM;
    int c = k / 9, q = k - c * 9;
    int dy = q / 3, dx = q - dy * 3;
    int y = (i >> 6) + dy - 1, x = (i & 63) + dx - 1;
    float v = 0.f;
    if ((unsigned)y < H && (unsigned)x < W) v = former[c * HW + y * W + x];
    __bf16 hi = (__bf16)v;
    __bf16 lo = (__bf16)(v - (float)hi);
    size_t base = (size_t)i * K3;
    A2[base + k] = hi;
    A2[base + KDIM + k] = lo;
    A2[base + 2 * KDIM + k] = hi;
}

// ---------------- normalized latter windows -> B2 = [WN_hi | WN_hi | WN_lo], den, mm ----------------
__global__ void build_winn_hilo(const float* __restrict__ latter, const float* __restrict__ mask,
                                const int* __restrict__ mask_thred_p,
                                __bf16* __restrict__ B2, float* __restrict__ den, float* __restrict__ mm) {
    int j = blockIdx.x;               // patch index
    int y0 = j >> 6, x0 = j & 63;
    __shared__ float red[256];
    float vals[5];
    float ss = 0.f;
    for (int t = 0; t < 5; ++t) {
        int k = threadIdx.x + t * 256;
        float v = 0.f;
        if (k < KDIM) {
            int c = k / 9, q = k - c * 9;
            int dy = q / 3, dx = q - dy * 3;
            int y = y0 + dy - 1, x = x0 + dx - 1;
            if ((unsigned)y < H && (unsigned)x < W) v = latter[c * HW + y * W + x];
        }
        vals[t] = v;
        ss += v * v;
    }
    red[threadIdx.x] = ss;
    __syncthreads();
    for (int s = 128; s > 0; s >>= 1) {
        if (threadIdx.x < s) red[threadIdx.x] += red[threadIdx.x + s];
        __syncthreads();
    }
    float d = fmaxf(sqrtf(red[0]), 1e-4f);
    float inv = 1.f / d;
    size_t base = (size_t)j * K3;
    for (int t = 0; t < 5; ++t) {
        int k = threadIdx.x + t * 256;
        if (k < KDIM) {
            float v = vals[t] * inv;
            __bf16 hi = (__bf16)v;
            __bf16 lo = (__bf16)(v - (float)hi);
            B2[base + k] = hi;
            B2[base + KDIM + k] = hi;
            B2[base + 2 * KDIM + k] = lo;
        }
    }
    if (threadIdx.x == 0) {
        den[j] = d;
        float s = 0.f;
        for (int q = 0; q < 9; ++q) {
            int dy = q / 3, dx = q - dy * 3;
            int y = y0 + dy - 1, x = x0 + dx - 1;
            if ((unsigned)y < H && (unsigned)x < W) s += mask[y * W + x];
        }
        float mmean = s / 9.f;
        float thr = (float)mask_thred_p[0] / 9.f;
        mm[j] = (mmean <= thr) ? 1.f : 0.f;
    }
}

// ---------------- MFMA bf16 NT GEMM: C[M,N] = A[M,K] * B[N,K]^T (fp32 out) ----------------
// 128x128 tile, BK=32, 4 waves each computing 64x64 via 4x4 frags of 16x16x32.
__launch_bounds__(256)
__global__ void gemm_bf16_nt(const __bf16* __restrict__ A, const __bf16* __restrict__ B,
                             float* __restrict__ C, int K, int ldc) {
    __shared__ __bf16 As[128 * 32];
    __shared__ __bf16 Bs[128 * 32];
    int tid = threadIdx.x;
    int wave = tid >> 6, lane = tid & 63;
    int quad = lane >> 4, lr = lane & 15;
    int wr = wave >> 1, wc = wave & 1;
    int i0 = blockIdx.y * 128, j0 = blockIdx.x * 128;

    int c0 = tid, c1 = tid + 256;
    int rA0 = c0 >> 2, kA0 = (c0 & 3) * 8;
    int rA1 = c1 >> 2, kA1 = (c1 & 3) * 8;

    f32x4 acc[4][4];
    #pragma unroll
    for (int a = 0; a < 4; ++a)
        #pragma unroll
        for (int b = 0; b < 4; ++b) acc[a][b] = (f32x4){0.f, 0.f, 0.f, 0.f};

    const __bf16* Ab = A + (size_t)i0 * K;
    const __bf16* Bb = B + (size_t)j0 * K;

    for (int k0 = 0; k0 < K; k0 += 32) {
        __syncthreads();
        gl_lds16(Ab + (size_t)rA0 * K + k0 + kA0, As + c0 * 8);
        gl_lds16(Ab + (size_t)rA1 * K + k0 + kA1, As + c1 * 8);
        gl_lds16(Bb + (size_t)rA0 * K + k0 + kA0, Bs + c0 * 8);
        gl_lds16(Bb + (size_t)rA1 * K + k0 + kA1, Bs + c1 * 8);
        __syncthreads();
        bf16x8 af[4], bfr[4];
        #pragma unroll
        for (int mi = 0; mi < 4; ++mi)
            af[mi] = *(const bf16x8*)(As + (wr * 64 + mi * 16 + lr) * 32 + quad * 8);
        #pragma unroll
        for (int ni = 0; ni < 4; ++ni)
            bfr[ni] = *(const bf16x8*)(Bs + (wc * 64 + ni * 16 + lr) * 32 + quad * 8);
        #pragma unroll
        for (int mi = 0; mi < 4; ++mi)
            #pragma unroll
            for (int ni = 0; ni < 4; ++ni)
                acc[mi][ni] = __builtin_amdgcn_mfma_f32_16x16x32_bf16(af[mi], bfr[ni], acc[mi][ni], 0, 0, 0);
    }

    #pragma unroll
    for (int mi = 0; mi < 4; ++mi) {
        #pragma unroll
        for (int r = 0; r < 4; ++r) {
            int row = i0 + wr * 64 + mi * 16 + quad * 4 + r;
            float* Cr = C + (size_t)row * ldc + j0 + wc * 64 + lr;
            #pragma unroll
            for (int ni = 0; ni < 4; ++ni)
                Cr[ni * 16] = acc[mi][ni][r];
        }
    }
}

// ---------------- pass A: E1[g,h] = diagbox3(S)[rm(g), rm(h)] ----------------
// diagbox3(S)[p,q] = sum_{d1 in {-1,0,1}, p+d1,q+d1 in range} S[p+d1, q+d1]
__launch_bounds__(256)
__global__ void diag_perm(const float* __restrict__ S, float* __restrict__ E1) {
    int g = blockIdx.x;
    int p = ((g & 63) << 6) | (g >> 6);   // rm(g)
    __shared__ float lds[3][64 * 65];
    for (int rr = 0; rr < 3; ++rr) {
        int pr = p + rr - 1;
        bool v = (unsigned)pr < HW;
        const float* Sr = S + (size_t)pr * HW;
        for (int idx = threadIdx.x; idx < HW; idx += 256) {
            float val = v ? Sr[idx] : 0.f;
            lds[rr][(idx & 63) * 65 + (idx >> 6)] = val;  // swizzled store (transpose layout)
        }
    }
    __syncthreads();
    for (int h = threadIdx.x; h < HW; h += 256) {
        int q = ((h & 63) << 6) | (h >> 6);  // rm(h)
        float s = 0.f;
        #pragma unroll
        for (int d1 = -1; d1 <= 1; ++d1) {
            int pp = p + d1, qq = q + d1;
            if ((unsigned)pp < HW && (unsigned)qq < HW)
                s += lds[d1 + 1][(qq & 63) * 65 + (qq >> 6)];
        }
        E1[(size_t)g * HW + h] = s;
    }
}

// ---------------- pass B: D2 = diagbox3(E1); softmax over h; *mm*den; bf16 out ----------------
__launch_bounds__(256)
__global__ void diag_softmax(const float* __restrict__ E1, const float* __restrict__ mm,
                             const float* __restrict__ den, __bf16* __restrict__ YB) {
    int g = blockIdx.x;
    __shared__ float red[256];
    float lv[16], sv[16];
    float lmax = -1e30f;
    #pragma unroll
    for (int t = 0; t < 16; ++t) {
        int h = threadIdx.x + t * 256;
        float s = 0.f;
        #pragma unroll
        for (int d2 = -1; d2 <= 1; ++d2) {
            int gg = g + d2, hh = h + d2;
            if ((unsigned)gg < HW && (unsigned)hh < HW)
                s += E1[(size_t)gg * HW + hh];
        }
        int j = ((h & 63) << 6) | (h >> 6);  // rm(h)
        float m = mm[j];
        float l = 10.f * s * m;
        lv[t] = l;
        sv[t] = m * den[j];
        lmax = fmaxf(lmax, l);
    }
    red[threadIdx.x] = lmax;
    __syncthreads();
    for (int s = 128; s > 0; s >>= 1) {
        if (threadIdx.x < s) red[threadIdx.x] = fmaxf(red[threadIdx.x], red[threadIdx.x + s]);
        __syncthreads();
    }
    float M = red[0];
    __syncthreads();
    float ev[16];
    float ssum = 0.f;
    #pragma unroll
    for (int t = 0; t < 16; ++t) {
        ev[t] = expf(lv[t] - M);
        ssum += ev[t];
    }
    red[threadIdx.x] = ssum;
    __syncthreads();
    for (int s = 128; s > 0; s >>= 1) {
        if (threadIdx.x < s) red[threadIdx.x] += red[threadIdx.x + s];
        __syncthreads();
    }
    float inv = 1.f / red[0];
    #pragma unroll
    for (int t = 0; t < 16; ++t) {
        int h = threadIdx.x + t * 256;
        YB[(size_t)g * HW + h] = (__bf16)(ev[t] * inv * sv[t]);
    }
}

// ---------------- WNT[n, h] = WN_hi[rm(h)][n]  (bf16, K-contiguous for GEMM2) ----------------
__launch_bounds__(256)
__global__ void wnt_transpose(const __bf16* __restrict__ B2, __bf16* __restrict__ WNT) {
    int bx = blockIdx.x;  // h-tile (64 wide): h = bx*64 + l -> j = l*64 + bx
    int by = blockIdx.y;  // n-tile
    int n0 = by * 64;
    __shared__ unsigned short tile[64][72];  // pitch 72 ushorts = 144B (16B aligned)
    for (int c = threadIdx.x; c < 512; c += 256) {
        int l = c >> 3, seg = c & 7;
        int j = l * 64 + bx;
        uint4 v = *(const uint4*)(B2 + (size_t)j * K3 + n0 + seg * 8);
        *(uint4*)&tile[l][seg * 8] = v;
    }
    __syncthreads();
    for (int c = threadIdx.x; c < 512; c += 256) {
        int r = c >> 3, seg = c & 7;
        unsigned short tmp[8];
        #pragma unroll
        for (int u = 0; u < 8; ++u) tmp[u] = tile[seg * 8 + u][r];
        *(uint4*)(WNT + (size_t)(n0 + r) * HW + bx * 64 + seg * 8) = *(uint4*)tmp;
    }
}

// ---------------- fold contrib (rows indexed by g=cm(pixel)) into shift output ----------------
__global__ void fold_out(const float* __restrict__ C2, float* __restrict__ outb) {
    int idx = blockIdx.x * blockDim.x + threadIdx.x; // over CH*HW
    if (idx >= CH * HW) return;
    int c = idx >> 12;
    int pix = idx & 4095;
    int y = pix >> 6, x = pix & 63;
    float s = 0.f;
    #pragma unroll
    for (int dy = 0; dy < 3; ++dy)
        #pragma unroll
        for (int dx = 0; dx < 3; ++dx) {
            int yy = y + 1 - dy, xx = x + 1 - dx;
            if ((unsigned)yy < H && (unsigned)xx < W)
                s += C2[(size_t)(xx * 64 + yy) * KDIM + c * 9 + dy * 3 + dx];
        }
    outb[(size_t)(CIN + c) * HW + pix] = s * (1.f / 9.f);
}

extern "C" void kernel_launch(void* const* d_in, const int* in_sizes, int n_in,
                              void* d_out, int out_size, void* d_ws, size_t ws_size,
                              hipStream_t stream) {
    const float* x = (const float*)d_in[0];
    const float* mask = (const float*)d_in[1];
    const int* mask_thred = (const int*)d_in[3];
    float* out = (float*)d_out;

    char* ws = (char*)d_ws;
    __bf16* A2 = (__bf16*)(ws);                         // 28,311,552 B
    __bf16* B2 = (__bf16*)(ws + 28311552);              // 28,311,552 B
    float*  S  = (float*)(ws + 56623104);               // 67,108,864 B
    float*  E1 = (float*)(ws + 123731968);              // 67,108,864 B
    float* den = (float*)(ws + 190840832);              // 16,384 B
    float* mmb = (float*)(ws + 190857216);              // 16,384 B
    // aliases (lifetimes disjoint): YB over S; WNT + C2 over E1
    __bf16* YB  = (__bf16*)S;                           // 32 MB
    __bf16* WNT = (__bf16*)E1;                          // 9.4 MB
    float*  C2  = (float*)(ws + 123731968 + 9437184);   // 18.9 MB

    copy_passthrough<<<(NB * CIN * HW + 255) / 256, 256, 0, stream>>>(x, out);

    for (int b = 0; b < NB; ++b) {
        const float* xb = x + (size_t)b * CIN * HW;
        const float* former = xb;
        const float* latter = xb + (size_t)CH * HW;
        const float* maskb = mask + (size_t)b * HW;
        float* outb = out + (size_t)b * COUT * HW;

        build_patches_hilo<<<(HW * KDIM + 255) / 256, 256, 0, stream>>>(former, A2);
        build_winn_hilo<<<HW, 256, 0, stream>>>(latter, maskb, mask_thred, B2, den, mmb);
        gemm_bf16_nt<<<dim3(32, 32), 256, 0, stream>>>(A2, B2, S, K3, HW);
        diag_perm<<<HW, 256, 0, stream>>>(S, E1);
        diag_softmax<<<HW, 256, 0, stream>>>(E1, mmb, den, YB);
        wnt_transpose<<<dim3(64, KDIM / 64), 256, 0, stream>>>(B2, WNT);
        gemm_bf16_nt<<<dim3(KDIM / 128, 32), 256, 0, stream>>>(YB, WNT, C2, HW, KDIM);
        fold_out<<<(CH * HW + 255) / 256, 256, 0, stream>>>(C2, outb);
    }
}